// Round 4
// baseline (257.161 us; speedup 1.0000x reference)
//
#include <hip/hip_runtime.h>
#include <math.h>

#define N_IN  128
#define N_HID 128
#define N_OUT 64
#define NBLK 256   // mega-kernel grid (1 block/CU, co-resident)
#define NTHR 256

typedef _Float16 f16x8 __attribute__((ext_vector_type(8)));
typedef _Float16 f16x4 __attribute__((ext_vector_type(4)));
typedef float f32x4 __attribute__((ext_vector_type(4)));

// ---------------- grid barrier (state memset to 0 before launch) ----------------
__device__ inline void grid_bar(int* cnt, int* sense, int target) {
  __syncthreads();
  if (threadIdx.x == 0) {
    __threadfence();
    int a = atomicAdd(cnt, 1);
    if (a == NBLK - 1) {
      atomicExch(cnt, 0);
      __threadfence();
      atomicAdd(sense, 1);
    }
    while (__hip_atomic_load(sense, __ATOMIC_ACQUIRE, __HIP_MEMORY_SCOPE_AGENT) < target)
      __builtin_amdgcn_s_sleep(2);
  }
  __syncthreads();
}

// ---------------- W fragment pack ----------------
// frag elem j of lane l, k-step s, n-tile t = W[s*32 + (l>>4)*8 + j][t*16 + (l&15)]
__device__ inline void pack_one(const float* __restrict__ W, _Float16* __restrict__ Wp,
                                int N, int K, int idx) {
  int l = idx & 63;
  int ts = idx >> 6;
  int KS = K / 32;
  int t = ts / KS, s = ts - t * KS;
  int col = t * 16 + (l & 15);
  int k0 = s * 32 + (l >> 4) * 8;
  f16x8 f;
#pragma unroll
  for (int j = 0; j < 8; ++j) f[j] = (_Float16)W[(size_t)(k0 + j) * N + col];
  *reinterpret_cast<f16x8*>(&Wp[(size_t)idx * 8]) = f;
}

// ---------------- CSR build + weight pack, single kernel ----------------
__global__ __launch_bounds__(NTHR) void k_csr_mega(
    const int* __restrict__ src, const int* __restrict__ dst, int E, int n,
    const float* __restrict__ W1, const float* __restrict__ W2,
    const float* __restrict__ W3, _Float16* __restrict__ Wp1,
    _Float16* __restrict__ Wp2, _Float16* __restrict__ Wp3,
    int* __restrict__ cnt, int* __restrict__ rowptr, float* __restrict__ dinv,
    int* __restrict__ csr, int* __restrict__ bsum, int* __restrict__ bar) {
  __shared__ int sh[NTHR];
  int gid = blockIdx.x * NTHR + threadIdx.x;
  const int gstride = NBLK * NTHR;

  // P0: zero cnt + pack weights + rowptr[n]=E
  for (int i = gid; i < n; i += gstride) cnt[i] = 0;
  if (gid < 2048) pack_one(W1, Wp1, N_HID, N_IN, gid);
  else if (gid < 4096) pack_one(W2, Wp2, N_HID, N_HID, gid - 2048);
  else if (gid < 5120) pack_one(W3, Wp3, N_OUT, N_HID, gid - 4096);
  if (gid == 0) rowptr[n] = E;
  grid_bar(bar, bar + 1, 1);

  // P1: degree histogram
  int quads = E >> 2;
  for (int q = gid; q < quads; q += gstride) {
    int4 d = reinterpret_cast<const int4*>(dst)[q];
    atomicAdd(&cnt[d.x], 1); atomicAdd(&cnt[d.y], 1);
    atomicAdd(&cnt[d.z], 1); atomicAdd(&cnt[d.w], 1);
  }
  if (gid == 0)
    for (int i = quads << 2; i < E; ++i) atomicAdd(&cnt[dst[i]], 1);
  grid_bar(bar, bar + 1, 2);

  // P2: per-512-chunk partial sums
  int nchunk = (n + 511) >> 9;
  if (blockIdx.x < nchunk) {
    int base = blockIdx.x << 9;
    int t = threadIdx.x;
    int v = 0;
    if (base + t < n) v = cnt[base + t];
    if (base + t + 256 < n) v += cnt[base + t + 256];
    sh[t] = v;
    __syncthreads();
    for (int o = 128; o > 0; o >>= 1) {
      if (t < o) sh[t] += sh[t + o];
      __syncthreads();
    }
    if (t == 0) bsum[blockIdx.x] = sh[0];
  }
  grid_bar(bar, bar + 1, 3);

  // P3: exclusive scan of bsum (block 0; nchunk <= 128 for n=50000)
  if (blockIdx.x == 0) {
    int t = threadIdx.x;
    if (nchunk <= 128) {
      int v0 = 0;
      if (t < 128) { v0 = (t < nchunk) ? bsum[t] : 0; sh[t] = v0; }
      __syncthreads();
      for (int o = 1; o < 128; o <<= 1) {
        int u = 0;
        if (t < 128 && t >= o) u = sh[t - o];
        __syncthreads();
        if (t < 128) sh[t] += u;
        __syncthreads();
      }
      if (t < nchunk) bsum[t] = sh[t] - v0;
    } else if (t == 0) {
      int acc = 0;
      for (int i = 0; i < nchunk; ++i) { int v = bsum[i]; bsum[i] = acc; acc += v; }
    }
  }
  grid_bar(bar, bar + 1, 4);

  // P4: intra-chunk scan -> rowptr, dinv
  if (blockIdx.x < nchunk) {
    int base = blockIdx.x << 9;
    int t = threadIdx.x;
    int i0 = base + 2 * t, i1 = i0 + 1;
    int e0 = (i0 < n) ? cnt[i0] : 0;
    int e1 = (i1 < n) ? cnt[i1] : 0;
    int p = e0 + e1;
    sh[t] = p;
    __syncthreads();
    for (int o = 1; o < 256; o <<= 1) {
      int u = (t >= o) ? sh[t - o] : 0;
      __syncthreads();
      sh[t] += u;
      __syncthreads();
    }
    int excl = sh[t] - p + bsum[blockIdx.x];
    if (i0 < n) { rowptr[i0] = excl;      dinv[i0] = rsqrtf((float)e0 + 1.f); }
    if (i1 < n) { rowptr[i1] = excl + e0; dinv[i1] = rsqrtf((float)e1 + 1.f); }
  }
  grid_bar(bar, bar + 1, 5);

  // P5: fill CSR (consumes cnt via atomicSub)
  for (int q = gid; q < quads; q += gstride) {
    int4 d = reinterpret_cast<const int4*>(dst)[q];
    int4 s4 = reinterpret_cast<const int4*>(src)[q];
    csr[rowptr[d.x] + atomicSub(&cnt[d.x], 1) - 1] = s4.x;
    csr[rowptr[d.y] + atomicSub(&cnt[d.y], 1) - 1] = s4.y;
    csr[rowptr[d.z] + atomicSub(&cnt[d.z], 1) - 1] = s4.z;
    csr[rowptr[d.w] + atomicSub(&cnt[d.w], 1) - 1] = s4.w;
  }
  if (gid == 0)
    for (int i = quads << 2; i < E; ++i) {
      int d = dst[i];
      csr[rowptr[d] + atomicSub(&cnt[d], 1) - 1] = src[i];
    }
}

// ---------------- MFMA GEMM (+ dinv row scale), fp32 A, out fp16 ----------------
__global__ __launch_bounds__(256) void k_gemm1(
    const float* __restrict__ A, const _Float16* __restrict__ Wp,
    const float* __restrict__ dinv, _Float16* __restrict__ out, int M) {
  constexpr int N = N_HID, K = 128, KS = K / 32, NT = N / 16;
  int lane = threadIdx.x & 63;
  int wave = threadIdx.x >> 6;
  int rowbase = blockIdx.x * 64 + wave * 16;
  int arow = rowbase + (lane & 15);
  int arc = arow < M ? arow : M - 1;
  int k0 = (lane >> 4) * 8;

  f16x8 afrag[KS];
#pragma unroll
  for (int s = 0; s < KS; ++s) {
    float4 v0 = *reinterpret_cast<const float4*>(&A[(size_t)arc * K + s * 32 + k0]);
    float4 v1 = *reinterpret_cast<const float4*>(&A[(size_t)arc * K + s * 32 + k0 + 4]);
    f16x8 f;
    f[0] = (_Float16)v0.x; f[1] = (_Float16)v0.y;
    f[2] = (_Float16)v0.z; f[3] = (_Float16)v0.w;
    f[4] = (_Float16)v1.x; f[5] = (_Float16)v1.y;
    f[6] = (_Float16)v1.z; f[7] = (_Float16)v1.w;
    afrag[s] = f;
  }

  f32x4 acc[NT] = {};
#pragma unroll
  for (int t = 0; t < NT; ++t)
#pragma unroll
    for (int s = 0; s < KS; ++s) {
      f16x8 b = *reinterpret_cast<const f16x8*>(&Wp[((size_t)(t * KS + s) * 64 + lane) * 8]);
      acc[t] = __builtin_amdgcn_mfma_f32_16x16x32_f16(afrag[s], b, acc[t], 0, 0, 0);
    }

  int crow = (lane >> 4) * 4;
  int col = lane & 15;
#pragma unroll
  for (int r = 0; r < 4; ++r) {
    int grow = rowbase + crow + r;
    if (grow < M) {
      float dv = dinv[grow];
#pragma unroll
      for (int t = 0; t < NT; ++t)
        out[(size_t)grow * N + t * 16 + col] = (_Float16)(acc[t][r] * dv);
    }
  }
}

// ---------------- Fused aggregation + GEMM (+ dinv epilogue) ----------------
// in: hs [n][128] (row-scaled); agg+bias+relu -> LDS 16x128 tile -> @ Wp -> out [n][NOUT]
template <int NOUT>
__global__ __launch_bounds__(256) void k_agg_gemm(
    const _Float16* __restrict__ hs, const float* __restrict__ dinv,
    const int* __restrict__ rowptr, const int* __restrict__ csr,
    const float* __restrict__ bias, const _Float16* __restrict__ Wp,
    _Float16* __restrict__ out, int n, int E) {
  constexpr int D = 128, KS = 4, NT = NOUT / 16, TPW = NT / 4;
  __shared__ __align__(16) _Float16 sm[16][D + 8];  // 272B row stride
  int lane = threadIdx.x & 63, wave = threadIdx.x >> 6;
  int h = lane >> 5;   // half-wave
  int j = lane & 31;   // dim slot [4j, 4j+4)
  int nodebase = blockIdx.x * 16;
  int nA = nodebase + wave * 4 + 2 * h;
  int nB = nA + 1;
  int cA = min(nA, n - 1), cB = min(nB, n - 1);
  float wsA = nA < n ? 1.f : 0.f, wsB = nB < n ? 1.f : 0.f;
  int begA = rowptr[cA], endA = nA < n ? rowptr[cA + 1] : begA;
  int begB = rowptr[cB], endB = nB < n ? rowptr[cB + 1] : begB;

  float accA[4], accB[4];
  {
    f16x4 sA = *reinterpret_cast<const f16x4*>(&hs[(size_t)cA * D + 4 * j]);
    f16x4 sB = *reinterpret_cast<const f16x4*>(&hs[(size_t)cB * D + 4 * j]);
#pragma unroll
    for (int k = 0; k < 4; ++k) {
      accA[k] = wsA * (float)sA[k];
      accB[k] = wsB * (float)sB[k];
    }
  }

  // 2 nodes per half-wave, 4-unrolled predicated: 8 independent gathers in flight
  int eA = begA, eB = begB;
  while (eA < endA || eB < endB) {
    int ia[4], ib[4];
    float wa[4], wb[4];
#pragma unroll
    for (int u = 0; u < 4; ++u) {
      int pA = eA + u, pB = eB + u;
      wa[u] = pA < endA ? 1.f : 0.f;
      wb[u] = pB < endB ? 1.f : 0.f;
      ia[u] = csr[min(pA, E - 1)];
      ib[u] = csr[min(pB, E - 1)];
    }
    f16x4 va[4], vb[4];
#pragma unroll
    for (int u = 0; u < 4; ++u) {
      va[u] = *reinterpret_cast<const f16x4*>(&hs[(size_t)ia[u] * D + 4 * j]);
      vb[u] = *reinterpret_cast<const f16x4*>(&hs[(size_t)ib[u] * D + 4 * j]);
    }
#pragma unroll
    for (int u = 0; u < 4; ++u)
#pragma unroll
      for (int k = 0; k < 4; ++k) {
        accA[k] = fmaf(wa[u], (float)va[u][k], accA[k]);
        accB[k] = fmaf(wb[u], (float)vb[u][k], accB[k]);
      }
    eA += 4; eB += 4;
  }

  // bias + relu -> LDS
  {
    float4 bv = *reinterpret_cast<const float4*>(&bias[4 * j]);
    const float* bp = reinterpret_cast<const float*>(&bv);
    float dvA = dinv[cA], dvB = dinv[cB];
    f16x4 pA, pB;
#pragma unroll
    for (int k = 0; k < 4; ++k) {
      pA[k] = (_Float16)fmaxf(dvA * accA[k] + bp[k], 0.f);
      pB[k] = (_Float16)fmaxf(dvB * accB[k] + bp[k], 0.f);
    }
    int lr = wave * 4 + 2 * h;
    *reinterpret_cast<f16x4*>(&sm[lr][4 * j]) = pA;
    *reinterpret_cast<f16x4*>(&sm[lr + 1][4 * j]) = pB;
  }
  __syncthreads();

  // MFMA: 16-row tile @ Wp; wave handles TPW n-tiles
  int r = lane & 15, k0 = (lane >> 4) * 8;
  f16x8 af[KS];
#pragma unroll
  for (int s = 0; s < KS; ++s)
    af[s] = *reinterpret_cast<const f16x8*>(&sm[r][s * 32 + k0]);

  f32x4 acc[TPW] = {};
#pragma unroll
  for (int tt = 0; tt < TPW; ++tt) {
    int t = wave * TPW + tt;
#pragma unroll
    for (int s = 0; s < KS; ++s) {
      f16x8 b = *reinterpret_cast<const f16x8*>(&Wp[((size_t)(t * KS + s) * 64 + lane) * 8]);
      acc[tt] = __builtin_amdgcn_mfma_f32_16x16x32_f16(af[s], b, acc[tt], 0, 0, 0);
    }
  }

  int crow = (lane >> 4) * 4, col = lane & 15;
#pragma unroll
  for (int r4 = 0; r4 < 4; ++r4) {
    int node = nodebase + crow + r4;
    if (node < n) {
      float dv = dinv[node];
#pragma unroll
      for (int tt = 0; tt < TPW; ++tt)
        out[(size_t)node * NOUT + (wave * TPW + tt) * 16 + col] =
            (_Float16)(acc[tt][r4] * dv);
    }
  }
}

// ---------------- Aggregation D=64 + log_softmax (quarter-wave per node) ----------------
__global__ __launch_bounds__(256) void k_agg64_lsm(
    const _Float16* __restrict__ hs, const float* __restrict__ dinv,
    const int* __restrict__ rowptr, const int* __restrict__ csr,
    const float* __restrict__ bias, float* __restrict__ out, int n, int E) {
  constexpr int D = 64;
  int lane = threadIdx.x & 63, wave = threadIdx.x >> 6;
  int q = lane >> 4, j = lane & 15;
  int node = blockIdx.x * 16 + wave * 4 + q;
  int c = min(node, n - 1);
  float ws = node < n ? 1.f : 0.f;
  int beg = rowptr[c], end = node < n ? rowptr[c + 1] : beg;

  float acc[4];
  {
    f16x4 sv = *reinterpret_cast<const f16x4*>(&hs[(size_t)c * D + 4 * j]);
#pragma unroll
    for (int k = 0; k < 4; ++k) acc[k] = ws * (float)sv[k];
  }

  for (int e = beg; e < end; e += 4) {
    int ii[4];
    float ww[4];
#pragma unroll
    for (int u = 0; u < 4; ++u) {
      int p = e + u;
      ww[u] = p < end ? 1.f : 0.f;
      ii[u] = csr[min(p, E - 1)];
    }
    f16x4 vv[4];
#pragma unroll
    for (int u = 0; u < 4; ++u)
      vv[u] = *reinterpret_cast<const f16x4*>(&hs[(size_t)ii[u] * D + 4 * j]);
#pragma unroll
    for (int u = 0; u < 4; ++u)
#pragma unroll
      for (int k = 0; k < 4; ++k) acc[k] = fmaf(ww[u], (float)vv[u][k], acc[k]);
  }

  float dv = dinv[c];
  float val[4];
#pragma unroll
  for (int k = 0; k < 4; ++k) val[k] = dv * acc[k] + bias[4 * j + k];

  // log_softmax within the 16-lane quarter (xor offsets < 16 stay in-quarter)
  float m = fmaxf(fmaxf(val[0], val[1]), fmaxf(val[2], val[3]));
#pragma unroll
  for (int o = 8; o > 0; o >>= 1) m = fmaxf(m, __shfl_xor(m, o));
  float ss = 0.f;
#pragma unroll
  for (int k = 0; k < 4; ++k) ss += expf(val[k] - m);
#pragma unroll
  for (int o = 8; o > 0; o >>= 1) ss += __shfl_xor(ss, o);
  float lse = m + logf(ss);

  if (node < n) {
    float4 o4 = make_float4(val[0] - lse, val[1] - lse, val[2] - lse, val[3] - lse);
    *reinterpret_cast<float4*>(&out[(size_t)node * D + 4 * j]) = o4;
  }
}

// ---------------- launch ----------------
extern "C" void kernel_launch(void* const* d_in, const int* in_sizes, int n_in,
                              void* d_out, int out_size, void* d_ws, size_t ws_size,
                              hipStream_t stream) {
  const float* x  = (const float*)d_in[0];
  const float* W1 = (const float*)d_in[1];
  const float* b1 = (const float*)d_in[2];
  const float* W2 = (const float*)d_in[3];
  const float* b2 = (const float*)d_in[4];
  const float* W3 = (const float*)d_in[5];
  const float* b3 = (const float*)d_in[6];
  const int*   ei = (const int*)d_in[7];

  int n = in_sizes[0] / N_IN;
  int E = in_sizes[7] / 2;
  const int* src = ei;
  const int* dst = ei + E;

  char* w = (char*)d_ws;
  size_t off = 0;
  auto alloc = [&](size_t bytes) -> void* {
    void* p = w + off;
    off = (off + bytes + 255) & ~(size_t)255;
    return p;
  };
  _Float16* hs1 = (_Float16*)alloc((size_t)n * N_HID * sizeof(_Float16));
  _Float16* hs2 = (_Float16*)alloc((size_t)n * N_HID * sizeof(_Float16));
  _Float16* hs3 = (_Float16*)alloc((size_t)n * N_OUT * sizeof(_Float16));
  _Float16* Wp1 = (_Float16*)alloc((size_t)N_IN * N_HID * sizeof(_Float16));
  _Float16* Wp2 = (_Float16*)alloc((size_t)N_HID * N_HID * sizeof(_Float16));
  _Float16* Wp3 = (_Float16*)alloc((size_t)N_HID * N_OUT * sizeof(_Float16));
  float* dinv = (float*)alloc((size_t)n * sizeof(float));
  int* cnt = (int*)alloc((size_t)n * sizeof(int));
  int* rowptr = (int*)alloc((size_t)(n + 1) * sizeof(int));
  int* csr = (int*)alloc((size_t)E * sizeof(int));
  int* bsum = (int*)alloc(4096);
  int* bar = (int*)alloc(256);

  hipMemsetAsync(bar, 0, 8, stream);
  k_csr_mega<<<NBLK, NTHR, 0, stream>>>(src, dst, E, n, W1, W2, W3, Wp1, Wp2, Wp3,
                                        cnt, rowptr, dinv, csr, bsum, bar);

  int gb = (n + 63) / 64;
  int ab = (n + 15) / 16;
  k_gemm1<<<gb, 256, 0, stream>>>(x, Wp1, dinv, hs1, n);
  k_agg_gemm<N_HID><<<ab, 256, 0, stream>>>(hs1, dinv, rowptr, csr, b1, Wp2, hs2, n, E);
  k_agg_gemm<N_OUT><<<ab, 256, 0, stream>>>(hs2, dinv, rowptr, csr, b2, Wp3, hs3, n, E);
  k_agg64_lsm<<<ab, 256, 0, stream>>>(hs3, dinv, rowptr, csr, b3, (float*)d_out, n, E);
}

// Round 5
// 166.636 us; speedup vs baseline: 1.5432x; 1.5432x over previous
//
#include <hip/hip_runtime.h>
#include <math.h>

#define N_IN  128
#define N_HID 128
#define N_OUT 64

typedef _Float16 f16x8 __attribute__((ext_vector_type(8)));
typedef _Float16 f16x4 __attribute__((ext_vector_type(4)));
typedef float f32x4 __attribute__((ext_vector_type(4)));

// ---------------- CSR build (separate kernels, full-grid occupancy) ----------------
__global__ void k_zero_int(int* __restrict__ p, int n) {
  int i = blockIdx.x * blockDim.x + threadIdx.x;
  if (i < n) p[i] = 0;
}

__global__ void k_hist(const int* __restrict__ dst, int E, int* __restrict__ cnt) {
  int i0 = (blockIdx.x * blockDim.x + threadIdx.x) * 4;
  int stride = gridDim.x * blockDim.x * 4;
  for (; i0 + 4 <= E; i0 += stride) {
    int4 d = *reinterpret_cast<const int4*>(&dst[i0]);
    atomicAdd(&cnt[d.x], 1);
    atomicAdd(&cnt[d.y], 1);
    atomicAdd(&cnt[d.z], 1);
    atomicAdd(&cnt[d.w], 1);
  }
  if (i0 < E)
    for (; i0 < E; ++i0) atomicAdd(&cnt[dst[i0]], 1);
}

#define SCAN_CHUNK 512

__global__ __launch_bounds__(SCAN_CHUNK) void k_block_sums(
    const int* __restrict__ cnt, int n, int* __restrict__ bsum) {
  __shared__ int s[SCAN_CHUNK];
  int i = blockIdx.x * SCAN_CHUNK + threadIdx.x;
  s[threadIdx.x] = (i < n) ? cnt[i] : 0;
  __syncthreads();
  for (int off = SCAN_CHUNK / 2; off > 0; off >>= 1) {
    if (threadIdx.x < off) s[threadIdx.x] += s[threadIdx.x + off];
    __syncthreads();
  }
  if (threadIdx.x == 0) bsum[blockIdx.x] = s[0];
}

__global__ __launch_bounds__(128) void k_scan_bsums(int* __restrict__ bsum, int nb) {
  __shared__ int s[128];
  int t = threadIdx.x;
  if (nb <= 128) {
    int v = (t < nb) ? bsum[t] : 0;
    s[t] = v;
    __syncthreads();
    for (int off = 1; off < 128; off <<= 1) {
      int u = (t >= off) ? s[t - off] : 0;
      __syncthreads();
      s[t] += u;
      __syncthreads();
    }
    if (t < nb) bsum[t] = s[t] - v;  // exclusive
  } else if (t == 0) {
    int acc = 0;
    for (int i = 0; i < nb; ++i) { int v = bsum[i]; bsum[i] = acc; acc += v; }
  }
}

__global__ __launch_bounds__(SCAN_CHUNK) void k_scan_final(
    const int* __restrict__ cnt, int n, const int* __restrict__ bsum,
    int* __restrict__ rowptr, float* __restrict__ dinv, int E) {
  __shared__ int s[SCAN_CHUNK];
  int i = blockIdx.x * SCAN_CHUNK + threadIdx.x;
  int v = (i < n) ? cnt[i] : 0;
  s[threadIdx.x] = v;
  __syncthreads();
  for (int off = 1; off < SCAN_CHUNK; off <<= 1) {
    int t = (threadIdx.x >= off) ? s[threadIdx.x - off] : 0;
    __syncthreads();
    s[threadIdx.x] += t;
    __syncthreads();
  }
  if (i < n) {
    rowptr[i] = bsum[blockIdx.x] + s[threadIdx.x] - v;  // exclusive
    dinv[i] = rsqrtf((float)v + 1.0f);                   // +1 self loop
    if (i == n - 1) rowptr[n] = E;
  }
}

// fill CSR; consumes cnt via atomicSub (cnt ends at zero)
__global__ void k_fill(const int* __restrict__ src, const int* __restrict__ dst, int E,
                       const int* __restrict__ rowptr, int* __restrict__ cnt,
                       int* __restrict__ csr) {
  int i0 = (blockIdx.x * blockDim.x + threadIdx.x) * 4;
  int stride = gridDim.x * blockDim.x * 4;
  for (; i0 + 4 <= E; i0 += stride) {
    int4 d = *reinterpret_cast<const int4*>(&dst[i0]);
    int4 sr = *reinterpret_cast<const int4*>(&src[i0]);
    csr[rowptr[d.x] + atomicSub(&cnt[d.x], 1) - 1] = sr.x;
    csr[rowptr[d.y] + atomicSub(&cnt[d.y], 1) - 1] = sr.y;
    csr[rowptr[d.z] + atomicSub(&cnt[d.z], 1) - 1] = sr.z;
    csr[rowptr[d.w] + atomicSub(&cnt[d.w], 1) - 1] = sr.w;
  }
  if (i0 < E)
    for (; i0 < E; ++i0) {
      int d = dst[i0];
      csr[rowptr[d] + atomicSub(&cnt[d], 1) - 1] = src[i0];
    }
}

// ---------------- W fragment pack (all three weights in one kernel) ----------------
// frag elem j of lane l, k-step s, n-tile t = W[s*32 + (l>>4)*8 + j][t*16 + (l&15)]
__device__ inline void pack_one(const float* __restrict__ W, _Float16* __restrict__ Wp,
                                int N, int K, int idx) {
  int l = idx & 63;
  int ts = idx >> 6;
  int KS = K / 32;
  int t = ts / KS, s = ts - t * KS;
  int col = t * 16 + (l & 15);
  int k0 = s * 32 + (l >> 4) * 8;
  f16x8 f;
#pragma unroll
  for (int j = 0; j < 8; ++j) f[j] = (_Float16)W[(size_t)(k0 + j) * N + col];
  *reinterpret_cast<f16x8*>(&Wp[(size_t)idx * 8]) = f;
}

__global__ void k_pack_all(const float* __restrict__ W1, const float* __restrict__ W2,
                           const float* __restrict__ W3, _Float16* __restrict__ Wp1,
                           _Float16* __restrict__ Wp2, _Float16* __restrict__ Wp3) {
  int idx = blockIdx.x * blockDim.x + threadIdx.x;
  if (idx < 2048) pack_one(W1, Wp1, N_HID, N_IN, idx);
  else if (idx < 4096) pack_one(W2, Wp2, N_HID, N_HID, idx - 2048);
  else if (idx < 5120) pack_one(W3, Wp3, N_OUT, N_HID, idx - 4096);
}

// ---------------- MFMA GEMM (+ dinv row scale), fp32 A, out fp16 ----------------
__global__ __launch_bounds__(256) void k_gemm1(
    const float* __restrict__ A, const _Float16* __restrict__ Wp,
    const float* __restrict__ dinv, _Float16* __restrict__ out, int M) {
  constexpr int N = N_HID, K = 128, KS = K / 32, NT = N / 16;
  int lane = threadIdx.x & 63;
  int wave = threadIdx.x >> 6;
  int rowbase = blockIdx.x * 64 + wave * 16;
  int arow = rowbase + (lane & 15);
  int arc = arow < M ? arow : M - 1;
  int k0 = (lane >> 4) * 8;

  f16x8 afrag[KS];
#pragma unroll
  for (int s = 0; s < KS; ++s) {
    float4 v0 = *reinterpret_cast<const float4*>(&A[(size_t)arc * K + s * 32 + k0]);
    float4 v1 = *reinterpret_cast<const float4*>(&A[(size_t)arc * K + s * 32 + k0 + 4]);
    f16x8 f;
    f[0] = (_Float16)v0.x; f[1] = (_Float16)v0.y;
    f[2] = (_Float16)v0.z; f[3] = (_Float16)v0.w;
    f[4] = (_Float16)v1.x; f[5] = (_Float16)v1.y;
    f[6] = (_Float16)v1.z; f[7] = (_Float16)v1.w;
    afrag[s] = f;
  }

  f32x4 acc[NT] = {};
#pragma unroll
  for (int t = 0; t < NT; ++t)
#pragma unroll
    for (int s = 0; s < KS; ++s) {
      f16x8 b = *reinterpret_cast<const f16x8*>(&Wp[((size_t)(t * KS + s) * 64 + lane) * 8]);
      acc[t] = __builtin_amdgcn_mfma_f32_16x16x32_f16(afrag[s], b, acc[t], 0, 0, 0);
    }

  int crow = (lane >> 4) * 4;
  int col = lane & 15;
#pragma unroll
  for (int r = 0; r < 4; ++r) {
    int grow = rowbase + crow + r;
    if (grow < M) {
      float dv = dinv[grow];
#pragma unroll
      for (int t = 0; t < NT; ++t)
        out[(size_t)grow * N + t * 16 + col] = (_Float16)(acc[t][r] * dv);
    }
  }
}

// ---------------- Fused aggregation + GEMM (+ dinv epilogue) ----------------
// in: hs [n][128] (row-scaled); agg+bias+relu -> LDS 16x128 tile -> @ Wp -> out [n][NOUT]
template <int NOUT>
__global__ __launch_bounds__(256) void k_agg_gemm(
    const _Float16* __restrict__ hs, const float* __restrict__ dinv,
    const int* __restrict__ rowptr, const int* __restrict__ csr,
    const float* __restrict__ bias, const _Float16* __restrict__ Wp,
    _Float16* __restrict__ out, int n, int E) {
  constexpr int D = 128, KS = 4, NT = NOUT / 16, TPW = NT / 4;
  __shared__ __align__(16) _Float16 sm[16][D + 8];  // 272B row stride
  int lane = threadIdx.x & 63, wave = threadIdx.x >> 6;
  int h = lane >> 5;   // half-wave
  int j = lane & 31;   // dim slot [4j, 4j+4)
  int nodebase = blockIdx.x * 16;
  int nA = nodebase + wave * 4 + 2 * h;
  int nB = nA + 1;
  int cA = min(nA, n - 1), cB = min(nB, n - 1);
  float wsA = nA < n ? 1.f : 0.f, wsB = nB < n ? 1.f : 0.f;
  int begA = rowptr[cA], endA = nA < n ? rowptr[cA + 1] : begA;
  int begB = rowptr[cB], endB = nB < n ? rowptr[cB + 1] : begB;

  float accA[4], accB[4];
  {
    f16x4 sA = *reinterpret_cast<const f16x4*>(&hs[(size_t)cA * D + 4 * j]);
    f16x4 sB = *reinterpret_cast<const f16x4*>(&hs[(size_t)cB * D + 4 * j]);
#pragma unroll
    for (int k = 0; k < 4; ++k) {
      accA[k] = wsA * (float)sA[k];
      accB[k] = wsB * (float)sB[k];
    }
  }

  // 2 nodes per half-wave, 4-unrolled predicated: 8 independent gathers in flight
  int eA = begA, eB = begB;
  while (eA < endA || eB < endB) {
    int ia[4], ib[4];
    float wa[4], wb[4];
#pragma unroll
    for (int u = 0; u < 4; ++u) {
      int pA = eA + u, pB = eB + u;
      wa[u] = pA < endA ? 1.f : 0.f;
      wb[u] = pB < endB ? 1.f : 0.f;
      ia[u] = csr[min(pA, E - 1)];
      ib[u] = csr[min(pB, E - 1)];
    }
    f16x4 va[4], vb[4];
#pragma unroll
    for (int u = 0; u < 4; ++u) {
      va[u] = *reinterpret_cast<const f16x4*>(&hs[(size_t)ia[u] * D + 4 * j]);
      vb[u] = *reinterpret_cast<const f16x4*>(&hs[(size_t)ib[u] * D + 4 * j]);
    }
#pragma unroll
    for (int u = 0; u < 4; ++u)
#pragma unroll
      for (int k = 0; k < 4; ++k) {
        accA[k] = fmaf(wa[u], (float)va[u][k], accA[k]);
        accB[k] = fmaf(wb[u], (float)vb[u][k], accB[k]);
      }
    eA += 4; eB += 4;
  }

  // bias + relu -> LDS
  {
    float4 bv = *reinterpret_cast<const float4*>(&bias[4 * j]);
    const float* bp = reinterpret_cast<const float*>(&bv);
    float dvA = dinv[cA], dvB = dinv[cB];
    f16x4 pA, pB;
#pragma unroll
    for (int k = 0; k < 4; ++k) {
      pA[k] = (_Float16)fmaxf(dvA * accA[k] + bp[k], 0.f);
      pB[k] = (_Float16)fmaxf(dvB * accB[k] + bp[k], 0.f);
    }
    int lr = wave * 4 + 2 * h;
    *reinterpret_cast<f16x4*>(&sm[lr][4 * j]) = pA;
    *reinterpret_cast<f16x4*>(&sm[lr + 1][4 * j]) = pB;
  }
  __syncthreads();

  // MFMA: 16-row tile @ Wp; wave handles TPW n-tiles
  int r = lane & 15, k0 = (lane >> 4) * 8;
  f16x8 af[KS];
#pragma unroll
  for (int s = 0; s < KS; ++s)
    af[s] = *reinterpret_cast<const f16x8*>(&sm[r][s * 32 + k0]);

  f32x4 acc[TPW] = {};
#pragma unroll
  for (int tt = 0; tt < TPW; ++tt) {
    int t = wave * TPW + tt;
#pragma unroll
    for (int s = 0; s < KS; ++s) {
      f16x8 b = *reinterpret_cast<const f16x8*>(&Wp[((size_t)(t * KS + s) * 64 + lane) * 8]);
      acc[tt] = __builtin_amdgcn_mfma_f32_16x16x32_f16(af[s], b, acc[tt], 0, 0, 0);
    }
  }

  int crow = (lane >> 4) * 4, col = lane & 15;
#pragma unroll
  for (int r4 = 0; r4 < 4; ++r4) {
    int node = nodebase + crow + r4;
    if (node < n) {
      float dv = dinv[node];
#pragma unroll
      for (int tt = 0; tt < TPW; ++tt)
        out[(size_t)node * NOUT + (wave * TPW + tt) * 16 + col] =
            (_Float16)(acc[tt][r4] * dv);
    }
  }
}

// ---------------- Aggregation D=64 + log_softmax (quarter-wave per node) ----------------
__global__ __launch_bounds__(256) void k_agg64_lsm(
    const _Float16* __restrict__ hs, const float* __restrict__ dinv,
    const int* __restrict__ rowptr, const int* __restrict__ csr,
    const float* __restrict__ bias, float* __restrict__ out, int n, int E) {
  constexpr int D = 64;
  int lane = threadIdx.x & 63, wave = threadIdx.x >> 6;
  int q = lane >> 4, j = lane & 15;
  int node = blockIdx.x * 16 + wave * 4 + q;
  int c = min(node, n - 1);
  float ws = node < n ? 1.f : 0.f;
  int beg = rowptr[c], end = node < n ? rowptr[c + 1] : beg;

  float acc[4];
  {
    f16x4 sv = *reinterpret_cast<const f16x4*>(&hs[(size_t)c * D + 4 * j]);
#pragma unroll
    for (int k = 0; k < 4; ++k) acc[k] = ws * (float)sv[k];
  }

  for (int e = beg; e < end; e += 4) {
    int ii[4];
    float ww[4];
#pragma unroll
    for (int u = 0; u < 4; ++u) {
      int p = e + u;
      ww[u] = p < end ? 1.f : 0.f;
      ii[u] = csr[min(p, E - 1)];
    }
    f16x4 vv[4];
#pragma unroll
    for (int u = 0; u < 4; ++u)
      vv[u] = *reinterpret_cast<const f16x4*>(&hs[(size_t)ii[u] * D + 4 * j]);
#pragma unroll
    for (int u = 0; u < 4; ++u)
#pragma unroll
      for (int k = 0; k < 4; ++k) acc[k] = fmaf(ww[u], (float)vv[u][k], acc[k]);
  }

  float dv = dinv[c];
  float val[4];
#pragma unroll
  for (int k = 0; k < 4; ++k) val[k] = dv * acc[k] + bias[4 * j + k];

  // log_softmax within the 16-lane quarter (xor offsets < 16 stay in-quarter)
  float m = fmaxf(fmaxf(val[0], val[1]), fmaxf(val[2], val[3]));
#pragma unroll
  for (int o = 8; o > 0; o >>= 1) m = fmaxf(m, __shfl_xor(m, o));
  float ss = 0.f;
#pragma unroll
  for (int k = 0; k < 4; ++k) ss += expf(val[k] - m);
#pragma unroll
  for (int o = 8; o > 0; o >>= 1) ss += __shfl_xor(ss, o);
  float lse = m + logf(ss);

  if (node < n) {
    float4 o4 = make_float4(val[0] - lse, val[1] - lse, val[2] - lse, val[3] - lse);
    *reinterpret_cast<float4*>(&out[(size_t)node * D + 4 * j]) = o4;
  }
}

// ---------------- launch ----------------
extern "C" void kernel_launch(void* const* d_in, const int* in_sizes, int n_in,
                              void* d_out, int out_size, void* d_ws, size_t ws_size,
                              hipStream_t stream) {
  const float* x  = (const float*)d_in[0];
  const float* W1 = (const float*)d_in[1];
  const float* b1 = (const float*)d_in[2];
  const float* W2 = (const float*)d_in[3];
  const float* b2 = (const float*)d_in[4];
  const float* W3 = (const float*)d_in[5];
  const float* b3 = (const float*)d_in[6];
  const int*   ei = (const int*)d_in[7];

  int n = in_sizes[0] / N_IN;
  int E = in_sizes[7] / 2;
  const int* src = ei;
  const int* dst = ei + E;

  char* w = (char*)d_ws;
  size_t off = 0;
  auto alloc = [&](size_t bytes) -> void* {
    void* p = w + off;
    off = (off + bytes + 255) & ~(size_t)255;
    return p;
  };
  _Float16* hs1 = (_Float16*)alloc((size_t)n * N_HID * sizeof(_Float16));
  _Float16* hs2 = (_Float16*)alloc((size_t)n * N_HID * sizeof(_Float16));
  _Float16* hs3 = (_Float16*)alloc((size_t)n * N_OUT * sizeof(_Float16));
  _Float16* Wp1 = (_Float16*)alloc((size_t)N_IN * N_HID * sizeof(_Float16));
  _Float16* Wp2 = (_Float16*)alloc((size_t)N_HID * N_HID * sizeof(_Float16));
  _Float16* Wp3 = (_Float16*)alloc((size_t)N_HID * N_OUT * sizeof(_Float16));
  float* dinv = (float*)alloc((size_t)n * sizeof(float));
  int* cnt = (int*)alloc((size_t)n * sizeof(int));
  int* rowptr = (int*)alloc((size_t)(n + 1) * sizeof(int));
  int* csr = (int*)alloc((size_t)E * sizeof(int));
  int* bsum = (int*)alloc(4096);

  // ---- CSR by dst (+ degrees, dinv) ----
  k_zero_int<<<(n + 255) / 256, 256, 0, stream>>>(cnt, n);
  {
    int blocks = min((E / 4 + 255) / 256, 1024);
    k_hist<<<blocks, 256, 0, stream>>>(dst, E, cnt);
    int nb = (n + SCAN_CHUNK - 1) / SCAN_CHUNK;
    k_block_sums<<<nb, SCAN_CHUNK, 0, stream>>>(cnt, n, bsum);
    k_scan_bsums<<<1, 128, 0, stream>>>(bsum, nb);
    k_scan_final<<<nb, SCAN_CHUNK, 0, stream>>>(cnt, n, bsum, rowptr, dinv, E);
    k_fill<<<blocks, 256, 0, stream>>>(src, dst, E, rowptr, cnt, csr);
  }

  // ---- pack weights to fp16 fragment order ----
  k_pack_all<<<20, 256, 0, stream>>>(W1, W2, W3, Wp1, Wp2, Wp3);

  int gb = (n + 63) / 64;
  int ab = (n + 15) / 16;
  k_gemm1<<<gb, 256, 0, stream>>>(x, Wp1, dinv, hs1, n);
  k_agg_gemm<N_HID><<<ab, 256, 0, stream>>>(hs1, dinv, rowptr, csr, b1, Wp2, hs2, n, E);
  k_agg_gemm<N_OUT><<<ab, 256, 0, stream>>>(hs2, dinv, rowptr, csr, b2, Wp3, hs3, n, E);
  k_agg64_lsm<<<ab, 256, 0, stream>>>(hs3, dinv, rowptr, csr, b3, (float*)d_out, n, E);
}